// Round 1
// baseline (905.932 us; speedup 1.0000x reference)
//
#include <hip/hip_runtime.h>

// ---------------------------------------------------------------------------
// MemN2N temporal layer, MEM=64 BATCH=32 L=64 E=1024 H=1024 HOPS=3, fp32.
//
// Algebra: with S[j,b,e] = sum_l inputs[j,b,l,e],
//   s[b,j] = sum_e S[j,b,e]*w[b,e] + w[b,1024+j],  w[b,:] = u[b,:] @ [A;TA]^T
//   o[b,h] = sum_e r[b,e]*C[e,h] + sum_j p[b,j]*TC[j,h],  r[b,e]=sum_j p_j S[j,b,e]
// fp32 throughout keeps softmax-argmax stable (logits sigma~2048, near one-hot).
//
// R2 -> R3 (this round):
//  - u0 = qs@B folded into k_reduce's qs-blocks (hidden under the 512 MiB
//    inputs stream); k_u0 kernel + its atomic pass + u/w zeroing removed.
//  - All weight streams (B, At, C, TC) are float4 loads: 1 VMEM per 16 FMA
//    (was 1 per 4) -> 4x issue density in the latency-bound hop kernels.
//  - Split-k is atomic-free: k_w -> wpart[8] partials, k_o -> opart[16]
//    partials (exclusive slots, plain stores / RMW); consumers sum partials
//    during LDS staging. No zero passes anywhere.
//  - k_s + softmax + k_pr fused into k_spr (32 blocks x 1024 thr); r-phase
//    re-reads the same S rows L2-hot. sv round-trip removed.
//  - Launch count 14 -> 11.
// Diagnostic intent: if dur_us does not move (<3%), the timed region is
// floored by the harness ws-poison fill (334 us each) and we are at the
// harness floor, not a kernel limit.
// ---------------------------------------------------------------------------

#define NMEM 64
#define NBATCH 32
#define NL 64
#define NE 1024
#define NH 1024
#define NEP 1088   /* NE + NMEM: A' = [A ; TA] */
#define NHOPS 3

// workspace float offsets (all multiples of 4 -> 16B aligned)
#define OFF_S   0u                            /* S: 2048 x 1024            */
#define OFF_AT  (2048u*1024u)                 /* At: 1024 x 1088 (A'^T)    */
#define OFF_WP  (OFF_AT + 1024u*1088u)        /* wpart: 8 x 32 x 1088      */
#define OFF_OP  (OFF_WP + 8u*32u*1088u)       /* opart: 16 x 32 x 1024     */
#define OFF_U0  (OFF_OP + 16u*32u*1024u)      /* u0:    32 x 1024          */
#define OFF_P   (OFF_U0 + 32u*1024u)          /* p:     32 x 64            */
#define OFF_R   (OFF_P + 32u*64u)             /* r:     32 x 1024          */

// ---------------------------------------------------------------------------
// K_reduce: blocks 0..2047   : S[row,:] = sum_l inputs[row, l, :]  (512 MiB)
//           blocks 2048..2079: qs[b,:] = sum_l questions[b,l,:] (in LDS),
//                              then u0[b,:] = qs[b,:] @ B  (float4 B loads)
//           blocks 2080..2351: At[h,e'] = A'[e',h]  (LDS tile transpose)
// ---------------------------------------------------------------------------
__global__ __launch_bounds__(256) void k_reduce(
    const float* __restrict__ inputs, const float* __restrict__ questions,
    const float* __restrict__ A, const float* __restrict__ TA,
    const float* __restrict__ B,
    float* __restrict__ S, float* __restrict__ u0, float* __restrict__ At) {
  const int blk = blockIdx.x, t = threadIdx.x;
  __shared__ __align__(16) float tile[64][65];   // 16.6 KB, aliased as lq[1024]

  if (blk < 2048) {
    const float4* base = (const float4*)(inputs + (size_t)blk * (NL * NE));
    float4 acc = make_float4(0.f, 0.f, 0.f, 0.f);
#pragma unroll 8
    for (int l = 0; l < NL; ++l) {
      float4 v = base[l * (NE / 4) + t];
      acc.x += v.x; acc.y += v.y; acc.z += v.z; acc.w += v.w;
    }
    ((float4*)(S + (size_t)blk * NE))[t] = acc;
  } else if (blk < 2080) {
    const int b = blk - 2048;
    float* lq = &tile[0][0];                     // 1024 floats
    const float4* base = (const float4*)(questions + (size_t)b * (NL * NE));
    float4 acc = make_float4(0.f, 0.f, 0.f, 0.f);
#pragma unroll 8
    for (int l = 0; l < NL; ++l) {
      float4 v = base[l * (NE / 4) + t];
      acc.x += v.x; acc.y += v.y; acc.z += v.z; acc.w += v.w;
    }
    ((float4*)lq)[t] = acc;
    __syncthreads();
    // u0 row: thread t owns h = 4t..4t+3
    const float4* B4 = (const float4*)B;
    float4 ua = make_float4(0.f, 0.f, 0.f, 0.f);
#pragma unroll 8
    for (int e = 0; e < NE; ++e) {
      const float q = lq[e];
      const float4 bv = B4[(size_t)e * (NH / 4) + t];
      ua.x += q * bv.x; ua.y += q * bv.y; ua.z += q * bv.z; ua.w += q * bv.w;
    }
    ((float4*)(u0 + (size_t)b * NH))[t] = ua;
  } else {
    const int idx = blk - 2080;
    const int et = idx % 17;      // e'-tile of 64 (17*64 = 1088)
    const int ht = idx / 17;      // h-tile of 64  (16*64 = 1024)
    const int r0 = t >> 6, c = t & 63;
#pragma unroll
    for (int rr = r0; rr < 64; rr += 4) {
      const int e = et * 64 + rr, h = ht * 64 + c;
      tile[rr][c] = (e < NE) ? A[(size_t)e * NH + h] : TA[(size_t)(e - NE) * NH + h];
    }
    __syncthreads();
#pragma unroll
    for (int rr = r0; rr < 64; rr += 4) {
      const int h = ht * 64 + rr, e = et * 64 + c;
      At[(size_t)h * NEP + e] = tile[c][rr];
    }
  }
}

// ---------------------------------------------------------------------------
// K_w: wpart[z][b][ep'] = sum_{h in chunk z} u[b,h]*At[h,ep'], u = u0 + sum
// opart (prior hops).  grid (2 ep4-tiles, 8 b-grp of 4, 8 h-chunks of 128),
// 256 thr.  Thread owns 4 consecutive ep (one float4 of At row) x 4 batches.
// No atomics: exclusive partial slots, summed by k_spr while staging.
// ---------------------------------------------------------------------------
__global__ __launch_bounds__(256) void k_w(
    const float* __restrict__ At, const float* __restrict__ u0,
    const float* __restrict__ opart, float* __restrict__ wpart, int hop) {
  const int t = threadIdx.x;
  const int b0 = blockIdx.y * 4;
  const int z = blockIdx.z, h0 = z * 128;
  __shared__ float lu[4][128];
  for (int idx = t; idx < 512; idx += 256) {
    const int bb = idx >> 7, i = idx & 127;
    float v = u0[(size_t)(b0 + bb) * NH + h0 + i];
    if (hop > 0) {
#pragma unroll
      for (int zz = 0; zz < 16; ++zz)
        v += opart[((size_t)zz * NBATCH + b0 + bb) * NH + h0 + i];
    }
    lu[bb][i] = v;
  }
  __syncthreads();
  const int ep4 = blockIdx.x * 256 + t;          // float4 column of At
  if (ep4 >= NEP / 4) return;                    // x=1: only t<16 active
  const float4* At4 = (const float4*)At;
  float4 acc[4];
#pragma unroll
  for (int bb = 0; bb < 4; ++bb) acc[bb] = make_float4(0.f, 0.f, 0.f, 0.f);
#pragma unroll 8
  for (int i = 0; i < 128; ++i) {
    const float4 av = At4[(size_t)(h0 + i) * (NEP / 4) + ep4];
#pragma unroll
    for (int bb = 0; bb < 4; ++bb) {
      const float uv = lu[bb][i];
      acc[bb].x += uv * av.x; acc[bb].y += uv * av.y;
      acc[bb].z += uv * av.z; acc[bb].w += uv * av.w;
    }
  }
  float4* wp4 = (float4*)wpart;
#pragma unroll
  for (int bb = 0; bb < 4; ++bb)
    wp4[((size_t)z * NBATCH + b0 + bb) * (NEP / 4) + ep4] = acc[bb];
}

// ---------------------------------------------------------------------------
// K_spr: per batch b (32 blocks x 1024 thr):
//   lw = sum_z wpart[z][b][:]           (LDS, 1088)
//   s[j] = S[j,b,:].lw[:1024] + lw[1024+j]   (16 waves x 4 j, wave dots)
//   p = softmax(s)  (wave 0); write p
//   r[b,e] = sum_j p_j S[j,b,e]   (1024 thr, S rows L2-hot from s-phase)
// ---------------------------------------------------------------------------
__global__ __launch_bounds__(1024) void k_spr(
    const float* __restrict__ S, const float* __restrict__ wpart,
    float* __restrict__ p, float* __restrict__ r) {
  const int t = threadIdx.x;
  const int b = blockIdx.x;
  __shared__ __align__(16) float lw[NEP];
  __shared__ float sl[NMEM];
  __shared__ float lp[NMEM];
  {
    float v = 0.f;
#pragma unroll
    for (int z = 0; z < 8; ++z) v += wpart[((size_t)z * NBATCH + b) * NEP + t];
    lw[t] = v;
    if (t < NMEM) {
      float v2 = 0.f;
#pragma unroll
      for (int z = 0; z < 8; ++z)
        v2 += wpart[((size_t)z * NBATCH + b) * NEP + NE + t];
      lw[NE + t] = v2;
    }
  }
  __syncthreads();
  const int lane = t & 63, wv = t >> 6;
  const float4* lw4 = (const float4*)lw;
#pragma unroll
  for (int q = 0; q < 4; ++q) {
    const int j = wv * 4 + q;
    const float4* S4 = (const float4*)(S + (size_t)(j * NBATCH + b) * NE);
    float acc = 0.f;
#pragma unroll
    for (int i = 0; i < 4; ++i) {
      const float4 a = S4[i * 64 + lane];
      const float4 c = lw4[i * 64 + lane];
      acc += a.x * c.x + a.y * c.y + a.z * c.z + a.w * c.w;
    }
#pragma unroll
    for (int off = 32; off > 0; off >>= 1) acc += __shfl_xor(acc, off, 64);
    if (lane == 0) sl[j] = acc + lw[NE + j];
  }
  __syncthreads();
  if (t < NMEM) {                                  // wave 0
    const float s = sl[t];
    float m = s;
#pragma unroll
    for (int off = 32; off > 0; off >>= 1) m = fmaxf(m, __shfl_xor(m, off, 64));
    const float ex = __expf(s - m);
    float l = ex;
#pragma unroll
    for (int off = 32; off > 0; off >>= 1) l += __shfl_xor(l, off, 64);
    const float pv = ex / l;
    lp[t] = pv;
    p[(size_t)b * NMEM + t] = pv;
  }
  __syncthreads();
  float acc = 0.f;
#pragma unroll 8
  for (int j = 0; j < NMEM; ++j)
    acc += lp[j] * S[(size_t)(j * NBATCH + b) * NE + t];
  r[(size_t)b * NE + t] = acc;
}

// ---------------------------------------------------------------------------
// K_o: opart[z][b][h] (+)= sum_{e in chunk z} r[b,e]*C[e,h]
//                          (+ sum_j p[b,j]*TC[j,h] on z==0).
// grid (8 b-grp of 4, 16 e-chunks of 64), 256 thr.  Thread owns one float4
// of C row (h=4t..4t+3) x 4 batches.  hop==0 writes, later hops accumulate
// (exclusive slot -> plain RMW, no atomics).
// ---------------------------------------------------------------------------
__global__ __launch_bounds__(256) void k_o(
    const float* __restrict__ C, const float* __restrict__ TC,
    const float* __restrict__ r, const float* __restrict__ p,
    float* __restrict__ opart, int hop) {
  const int t = threadIdx.x;
  const int b0 = blockIdx.x * 4;
  const int z = blockIdx.y, e0 = z * 64;
  __shared__ float lr[4][64];
  __shared__ float lpp[4][64];
  {
    const int bb = t >> 6, i = t & 63;
    lr[bb][i] = r[(size_t)(b0 + bb) * NE + e0 + i];
    if (z == 0) lpp[bb][i] = p[(size_t)(b0 + bb) * NMEM + i];
  }
  __syncthreads();
  const float4* C4 = (const float4*)C;
  float4 acc[4];
#pragma unroll
  for (int bb = 0; bb < 4; ++bb) acc[bb] = make_float4(0.f, 0.f, 0.f, 0.f);
#pragma unroll 8
  for (int i = 0; i < 64; ++i) {
    const float4 cv = C4[(size_t)(e0 + i) * (NH / 4) + t];
#pragma unroll
    for (int bb = 0; bb < 4; ++bb) {
      const float rv = lr[bb][i];
      acc[bb].x += rv * cv.x; acc[bb].y += rv * cv.y;
      acc[bb].z += rv * cv.z; acc[bb].w += rv * cv.w;
    }
  }
  if (z == 0) {
    const float4* TC4 = (const float4*)TC;
#pragma unroll 8
    for (int j = 0; j < NMEM; ++j) {
      const float4 tv = TC4[(size_t)j * (NH / 4) + t];
#pragma unroll
      for (int bb = 0; bb < 4; ++bb) {
        const float pv = lpp[bb][j];
        acc[bb].x += pv * tv.x; acc[bb].y += pv * tv.y;
        acc[bb].z += pv * tv.z; acc[bb].w += pv * tv.w;
      }
    }
  }
  float4* op4 = (float4*)opart;
#pragma unroll
  for (int bb = 0; bb < 4; ++bb) {
    const size_t idx = ((size_t)z * NBATCH + b0 + bb) * (NH / 4) + t;
    if (hop == 0) {
      op4[idx] = acc[bb];
    } else {
      float4 o = op4[idx];
      o.x += acc[bb].x; o.y += acc[bb].y; o.z += acc[bb].z; o.w += acc[bb].w;
      op4[idx] = o;
    }
  }
}

// ---------------------------------------------------------------------------
// K_final: u[b,h] = u0[b,h] + sum_z opart[z][b][h].  32 blocks x 256 thr.
// ---------------------------------------------------------------------------
__global__ __launch_bounds__(256) void k_final(
    const float* __restrict__ u0, const float* __restrict__ opart,
    float* __restrict__ u) {
  const int slot = blockIdx.x * 256 + threadIdx.x;   // 0..8191 float4 slots
  const int b = slot >> 8, h4 = slot & 255;
  float4 v = ((const float4*)u0)[slot];
  const float4* op4 = (const float4*)opart;
#pragma unroll
  for (int z = 0; z < 16; ++z) {
    const float4 o = op4[((size_t)z * NBATCH + b) * (NH / 4) + h4];
    v.x += o.x; v.y += o.y; v.z += o.z; v.w += o.w;
  }
  ((float4*)u)[slot] = v;
}

// ---------------------------------------------------------------------------
extern "C" void kernel_launch(void* const* d_in, const int* in_sizes, int n_in,
                              void* d_out, int out_size, void* d_ws, size_t ws_size,
                              hipStream_t stream) {
  (void)in_sizes; (void)n_in; (void)out_size; (void)ws_size;
  const float* inputs    = (const float*)d_in[0];
  const float* questions = (const float*)d_in[1];
  const float* A         = (const float*)d_in[2];
  const float* C         = (const float*)d_in[3];
  const float* B         = (const float*)d_in[4];
  const float* TA        = (const float*)d_in[5];
  const float* TC        = (const float*)d_in[6];
  float* u  = (float*)d_out;
  float* ws = (float*)d_ws;
  float* S     = ws + OFF_S;
  float* At    = ws + OFF_AT;
  float* wpart = ws + OFF_WP;
  float* opart = ws + OFF_OP;
  float* u0    = ws + OFF_U0;
  float* p     = ws + OFF_P;
  float* r     = ws + OFF_R;

  k_reduce<<<2048 + 32 + 272, 256, 0, stream>>>(inputs, questions, A, TA, B, S, u0, At);
  for (int hop = 0; hop < NHOPS; ++hop) {
    k_w<<<dim3(2, 8, 8), 256, 0, stream>>>(At, u0, opart, wpart, hop);
    k_spr<<<32, 1024, 0, stream>>>(S, wpart, p, r);
    k_o<<<dim3(8, 16), 256, 0, stream>>>(C, TC, r, p, opart, hop);
  }
  k_final<<<32, 256, 0, stream>>>(u0, opart, u);
}

// Round 2
// 902.046 us; speedup vs baseline: 1.0043x; 1.0043x over previous
//
#include <hip/hip_runtime.h>

// ---------------------------------------------------------------------------
// MemN2N temporal layer, MEM=64 BATCH=32 L=64 E=1024 H=1024 HOPS=3, fp32.
//
// Algebra: with S[j,b,e] = sum_l inputs[j,b,l,e],
//   s[b,j] = sum_e S[j,b,e]*w[b,e] + w[b,1024+j],  w[b,:] = u[b,:] @ [A;TA]^T
//   o[b,h] = sum_e r[b,e]*C[e,h] + sum_j p[b,j]*TC[j,h],  r[b,e]=sum_j p_j S[j,b,e]
// fp32 throughout keeps softmax-argmax stable (logits sigma~2048, near one-hot).
//
// R3 -> R4: R3 regressed (+106us) by shrinking hop-kernel grids (latency-bound
// kernels need CUs, not fewer launches). R4 = R2 structure (proven 799us:
// k_w 320 blk atomics, k_s 512 blk, k_o 256 blk) with launch cuts that KEEP
// parallelism:
//  - u0 folded into k_reduce as 32 independent blocks (own questions
//    re-reduction, exclusive u writes) -> hidden under the 512 MiB S-stream.
//  - k_pr fused into k_o (grid unchanged 256 blk): per-block softmax from sv
//    (redundant, trivial) + r-chunk staged from S in LDS. p/r buffers gone.
//  - launches 14 -> 10.
// ---------------------------------------------------------------------------

#define NMEM 64
#define NBATCH 32
#define NL 64
#define NE 1024
#define NH 1024
#define NEP 1088   /* NE + NMEM: A' = [A ; TA] */
#define NHOPS 3

// workspace float offsets (all multiples of 4 -> 16B aligned)
#define OFF_S   0u                            /* S: 2048 x 1024            */
#define OFF_AT  (2048u*1024u)                 /* At: 1024 x 1088 (A'^T)    */
#define OFF_W   (OFF_AT + 1024u*1088u)        /* w: 32 x 1088              */
#define OFF_SV  (OFF_W + 32u*1088u)           /* sv: 32 x 64               */

// ---------------------------------------------------------------------------
// K_reduce: blocks 0..2047   : S[row,:] = sum_l inputs[row, l, :]  (512 MiB)
//           blocks 2048..2079: u0-blocks: lq[4][1024] = sum_l questions
//                              (own re-reduction), u[b,h] = lq[b,:].B[:,h]
//                              (exclusive writes); ht==0 blocks zero w.
//           blocks 2080..2351: At[h,e'] = A'[e',h]  (LDS tile transpose)
// ---------------------------------------------------------------------------
__global__ __launch_bounds__(256) void k_reduce(
    const float* __restrict__ inputs, const float* __restrict__ questions,
    const float* __restrict__ A, const float* __restrict__ TA,
    const float* __restrict__ B,
    float* __restrict__ S, float* __restrict__ u, float* __restrict__ w,
    float* __restrict__ At) {
  const int blk = blockIdx.x, t = threadIdx.x;
  __shared__ __align__(16) float tile[64][65];   // 16.6 KB; u0-blocks alias 4096 floats

  if (blk < 2048) {
    const float4* base = (const float4*)(inputs + (size_t)blk * (NL * NE));
    float4 acc = make_float4(0.f, 0.f, 0.f, 0.f);
#pragma unroll 8
    for (int l = 0; l < NL; ++l) {
      float4 v = base[l * (NE / 4) + t];
      acc.x += v.x; acc.y += v.y; acc.z += v.z; acc.w += v.w;
    }
    ((float4*)(S + (size_t)blk * NE))[t] = acc;
  } else if (blk < 2080) {
    const int idx = blk - 2048;
    const int ht = idx & 3;             // h-tile of 256
    const int b0 = (idx >> 2) * 4;      // batch group of 4
    float* lq = &tile[0][0];            // [4][1024] flat (4096 <= 4160 floats)
    // re-reduce questions for this batch group (independent of other blocks)
    for (int slot = t; slot < 4096; slot += 256) {
      const int bb = slot >> 10, e = slot & 1023;
      const float* qp = questions + (size_t)(b0 + bb) * (NL * NE) + e;
      float a = 0.f;
#pragma unroll 8
      for (int l = 0; l < NL; ++l) a += qp[l * NE];
      lq[slot] = a;
    }
    // zero w rows for hop-0 atomics (one block per batch group: ht==0)
    if (ht == 0)
      for (int i = t; i < 4 * NEP; i += 256)
        w[(size_t)(b0 + i / NEP) * NEP + (i % NEP)] = 0.f;
    __syncthreads();
    const int h = ht * 256 + t;
    float acc[4] = {0.f, 0.f, 0.f, 0.f};
#pragma unroll 8
    for (int e = 0; e < NE; ++e) {
      const float bv = B[(size_t)e * NH + h];
#pragma unroll
      for (int bb = 0; bb < 4; ++bb) acc[bb] += lq[bb * 1024 + e] * bv;
    }
#pragma unroll
    for (int bb = 0; bb < 4; ++bb) u[(size_t)(b0 + bb) * NH + h] = acc[bb];
  } else {
    const int idx = blk - 2080;
    const int et = idx % 17;      // e'-tile of 64 (17*64 = 1088)
    const int ht = idx / 17;      // h-tile of 64  (16*64 = 1024)
    const int r0 = t >> 6, c = t & 63;
#pragma unroll
    for (int rr = r0; rr < 64; rr += 4) {
      const int e = et * 64 + rr, h = ht * 64 + c;
      tile[rr][c] = (e < NE) ? A[(size_t)e * NH + h] : TA[(size_t)(e - NE) * NH + h];
    }
    __syncthreads();
#pragma unroll
    for (int rr = r0; rr < 64; rr += 4) {
      const int h = ht * 64 + rr, e = et * 64 + c;
      At[(size_t)h * NEP + e] = tile[c][rr];
    }
  }
}

// ---------------------------------------------------------------------------
// K_w: w[b,e'] += sum_h u[b,h]*At[h,e'].  grid (5 ep-tiles, 8 b-grp of 4,
// 8 h-chunks of 128), 256 thr, guard ep<1088.  u chunk staged in LDS.
// (R2-exact: 320 blocks, atomics into pre-zeroed w.)
// ---------------------------------------------------------------------------
__global__ __launch_bounds__(256) void k_w(
    const float* __restrict__ At, const float* __restrict__ u,
    float* __restrict__ w) {
  const int t = threadIdx.x;
  const int ep = blockIdx.x * 256 + t;
  const int b0 = blockIdx.y * 4;
  const int h0 = blockIdx.z * 128;
  __shared__ float lu[4][128];
  for (int idx = t; idx < 512; idx += 256)
    lu[idx >> 7][idx & 127] = u[(size_t)(b0 + (idx >> 7)) * NH + h0 + (idx & 127)];
  __syncthreads();
  if (ep >= NEP) return;
  float acc[4] = {0.f, 0.f, 0.f, 0.f};
#pragma unroll 8
  for (int i = 0; i < 128; ++i) {
    const float av = At[(size_t)(h0 + i) * NEP + ep];
#pragma unroll
    for (int bb = 0; bb < 4; ++bb) acc[bb] += lu[bb][i] * av;
  }
#pragma unroll
  for (int bb = 0; bb < 4; ++bb) atomicAdd(&w[(size_t)(b0 + bb) * NEP + ep], acc[bb]);
}

// ---------------------------------------------------------------------------
// K_s: s[b,j] = S[j,b,:].w[b,:] + w[b,1024+j].  grid (16 j-grp, 32 b),
// 256 thr = 4 waves, one wave-dot (len 1024) per j.  (R2-exact.)
// ---------------------------------------------------------------------------
__global__ __launch_bounds__(256) void k_s(
    const float* __restrict__ S, const float* __restrict__ w,
    float* __restrict__ sv) {
  const int lane = threadIdx.x & 63, wv = threadIdx.x >> 6;
  const int j = blockIdx.x * 4 + wv, b = blockIdx.y;
  const float4* S4 = (const float4*)(S + (size_t)(j * NBATCH + b) * NE);
  const float4* w4 = (const float4*)(w + (size_t)b * NEP);
  float acc = 0.f;
#pragma unroll
  for (int i = 0; i < 4; ++i) {
    const int slot = i * 64 + lane;
    float4 a = S4[slot], c = w4[slot];
    acc += a.x * c.x + a.y * c.y + a.z * c.z + a.w * c.w;
  }
#pragma unroll
  for (int off = 32; off > 0; off >>= 1) acc += __shfl_xor(acc, off, 64);
  if (lane == 0) sv[(size_t)b * NMEM + j] = acc + w[(size_t)b * NEP + NE + j];
}

// ---------------------------------------------------------------------------
// K_o (fused k_pr+k_o): per block — softmax over sv (wave wv = batch bb),
// stage r-chunk lr[4][128] from S, then u[b,h] += sum_e lr*C[e,h]
// (+ sum_j lp*TC[j,h] on z==0).  grid (4 h-tiles, 8 b-grp of 4, 8 e-chunks
// of 128), 256 thr.  x==0,z==0 blocks re-zero w for the next hop.
// ---------------------------------------------------------------------------
__global__ __launch_bounds__(256) void k_o(
    const float* __restrict__ C, const float* __restrict__ TC,
    const float* __restrict__ S, const float* __restrict__ sv,
    float* __restrict__ u, float* __restrict__ w) {
  const int t = threadIdx.x;
  const int h = blockIdx.x * 256 + t;
  const int b0 = blockIdx.y * 4;
  const int e0 = blockIdx.z * 128;
  __shared__ float lp[4][64];
  __shared__ float lr[4][128];
  {
    // softmax for batch b0+wv, all 64 lanes (j = lane)
    const int lane = t & 63, wv = t >> 6;
    const float s = sv[(size_t)(b0 + wv) * NMEM + lane];
    float m = s;
#pragma unroll
    for (int off = 32; off > 0; off >>= 1) m = fmaxf(m, __shfl_xor(m, off, 64));
    const float ex = __expf(s - m);
    float l = ex;
#pragma unroll
    for (int off = 32; off > 0; off >>= 1) l += __shfl_xor(l, off, 64);
    lp[wv][lane] = ex / l;
  }
  __syncthreads();
  // stage r chunk: lr[bb][i] = sum_j lp[bb][j] * S[j,b0+bb,e0+i]
  for (int idx = t; idx < 512; idx += 256) {
    const int bb = idx >> 7, i = idx & 127;
    float acc = 0.f;
#pragma unroll 8
    for (int j = 0; j < NMEM; ++j)
      acc += lp[bb][j] * S[((size_t)j * NBATCH + b0 + bb) * NE + e0 + i];
    lr[bb][i] = acc;
  }
  __syncthreads();
  float acc[4] = {0.f, 0.f, 0.f, 0.f};
#pragma unroll 8
  for (int i = 0; i < 128; ++i) {
    const float cv = C[(size_t)(e0 + i) * NH + h];
#pragma unroll
    for (int bb = 0; bb < 4; ++bb) acc[bb] += lr[bb][i] * cv;
  }
  if (blockIdx.z == 0) {
#pragma unroll 8
    for (int j = 0; j < NMEM; ++j) {
      const float tcv = TC[(size_t)j * NH + h];
#pragma unroll
      for (int bb = 0; bb < 4; ++bb) acc[bb] += lp[bb][j] * tcv;
    }
  }
#pragma unroll
  for (int bb = 0; bb < 4; ++bb) atomicAdd(&u[(size_t)(b0 + bb) * NH + h], acc[bb]);
  // re-zero w rows for the next hop's atomics (one block per batch group)
  if (blockIdx.x == 0 && blockIdx.z == 0)
    for (int i = t; i < 4 * NEP; i += 256)
      w[(size_t)(b0 + i / NEP) * NEP + (i % NEP)] = 0.f;
}

// ---------------------------------------------------------------------------
extern "C" void kernel_launch(void* const* d_in, const int* in_sizes, int n_in,
                              void* d_out, int out_size, void* d_ws, size_t ws_size,
                              hipStream_t stream) {
  (void)in_sizes; (void)n_in; (void)out_size; (void)ws_size;
  const float* inputs    = (const float*)d_in[0];
  const float* questions = (const float*)d_in[1];
  const float* A         = (const float*)d_in[2];
  const float* C         = (const float*)d_in[3];
  const float* B         = (const float*)d_in[4];
  const float* TA        = (const float*)d_in[5];
  const float* TC        = (const float*)d_in[6];
  float* u  = (float*)d_out;
  float* ws = (float*)d_ws;
  float* S  = ws + OFF_S;
  float* At = ws + OFF_AT;
  float* w  = ws + OFF_W;
  float* sv = ws + OFF_SV;

  k_reduce<<<2048 + 32 + 272, 256, 0, stream>>>(inputs, questions, A, TA, B, S, u, w, At);
  for (int hop = 0; hop < NHOPS; ++hop) {
    k_w<<<dim3(5, 8, 8), 256, 0, stream>>>(At, u, w);
    k_s<<<dim3(16, 32), 256, 0, stream>>>(S, w, sv);
    k_o<<<dim3(4, 8, 8), 256, 0, stream>>>(C, TC, S, sv, u, w);
  }
}